// Round 2
// baseline (400.048 us; speedup 1.0000x reference)
//
#include <hip/hip_runtime.h>
#include <hip/hip_bf16.h>
#include <stdint.h>

#define T1 2048
#define T2 2048
#define NB 4
#define CC 1024

typedef __attribute__((ext_vector_type(4))) float   f32x4;
typedef __attribute__((ext_vector_type(8))) __bf16  bf16x8;
typedef __attribute__((ext_vector_type(8))) unsigned short u16x8;

__device__ __forceinline__ unsigned short f2bf(float f) {
    union { float f; uint32_t u; } x; x.f = f;
    uint32_t u = x.u;
    uint32_t r = (u + 0x7fffu + ((u >> 16) & 1u)) >> 16;
    return (unsigned short)r;
}

__device__ __forceinline__ float bf2f(unsigned short b) {
    return __uint_as_float(((uint32_t)b) << 16);
}

__device__ __forceinline__ void gll16(const void* g, void* l) {
    __builtin_amdgcn_global_load_lds((const __attribute__((address_space(1))) void*)g,
                                     (__attribute__((address_space(3))) void*)l, 16, 0, 0);
}

// ---------------- fused fp32 -> bf16 convert: wq,wk,wv,wu,x1,x2 -> contiguous bf16 ----------------
// dst flat element layout: [0,1M)=wq [1M,2M)=wk [2M,3M)=wv [3M,4M)=wu [4M,12M)=x1 [12M,20M)=x2
__global__ __launch_bounds__(256) void convall_k(const float* __restrict__ wq,
                                                 const float* __restrict__ wk,
                                                 const float* __restrict__ wv,
                                                 const float* __restrict__ wu,
                                                 const float* __restrict__ x1,
                                                 const float* __restrict__ x2,
                                                 unsigned short* __restrict__ dst) {
    size_t idx = ((size_t)blockIdx.x * 256 + threadIdx.x) * 8;
    const float* s;
    size_t off;
    if (idx < 4194304) {
        int wsel = (int)(idx >> 20);
        s = (wsel == 0) ? wq : (wsel == 1) ? wk : (wsel == 2) ? wv : wu;
        off = idx & 1048575;
    } else if (idx < 12582912) {
        s = x1; off = idx - 4194304;
    } else {
        s = x2; off = idx - 12582912;
    }
    f32x4 a = *(const f32x4*)(s + off);
    f32x4 b = *(const f32x4*)(s + off + 4);
    u16x8 o;
    o[0] = f2bf(a.x); o[1] = f2bf(a.y); o[2] = f2bf(a.z); o[3] = f2bf(a.w);
    o[4] = f2bf(b.x); o[5] = f2bf(b.y); o[6] = f2bf(b.z); o[7] = f2bf(b.w);
    *(u16x8*)(dst + idx) = o;
}

// ---------------- generic bf16 MFMA GEMM (A . B^T), m97-style 128^2 tile ----------------
// A: [M, KDIM] bf16 rows; B: [N, KDIM] bf16 rows. MODE controls epilogue mapping.
enum { M_PROJQ = 0, M_PROJK, M_PROJV, M_SCORES, M_PV, M_OUT };

template <int MODE, int KDIM>
__global__ __launch_bounds__(256) void gemm_bt(const unsigned short* __restrict__ Aptr,
                                               const unsigned short* __restrict__ Bptr,
                                               const float* __restrict__ bias,
                                               void* __restrict__ Out) {
    __shared__ unsigned short As[128 * 32];
    __shared__ unsigned short Bs[128 * 32];

    const int tid  = threadIdx.x;
    const int lane = tid & 63;
    const int w    = tid >> 6;
    const int wr   = w >> 1, wc = w & 1;
    const int m0   = blockIdx.y * 128;
    const int n0   = blockIdx.x * 128;
    const int z    = blockIdx.z;

    size_t aoff = 0, boff = 0;
    if constexpr (MODE == M_SCORES) { aoff = (size_t)z * T1 * CC; boff = (size_t)z * T2 * CC; }
    if constexpr (MODE == M_PV)     { aoff = (size_t)z * T1 * T2; boff = (size_t)z * CC * T2; }

    const unsigned short* Ab = Aptr + aoff;
    const unsigned short* Bb = Bptr + boff;

    f32x4 acc[4][4] = {};

    const int ln15 = lane & 15;
    const int l4   = lane >> 4;
    const int srow = tid >> 2, sseg = tid & 3;   // staging: 2 passes of 256 lanes

    for (int kt = 0; kt < KDIM; kt += 32) {
        __syncthreads();
#pragma unroll
        for (int p = 0; p < 2; ++p) {
            int c = p * 256 + tid;
            int row = p * 64 + srow;
            gll16(Ab + (size_t)(m0 + row) * KDIM + kt + sseg * 8, &As[c * 8]);
        }
#pragma unroll
        for (int p = 0; p < 2; ++p) {
            int c = p * 256 + tid;
            int row = p * 64 + srow;
            gll16(Bb + (size_t)(n0 + row) * KDIM + kt + sseg * 8, &Bs[c * 8]);
        }
        __syncthreads();
        bf16x8 af[4], bf[4];
#pragma unroll
        for (int i = 0; i < 4; ++i) {
            int arow = wr * 64 + i * 16 + ln15;
            af[i] = *(const bf16x8*)(&As[arow * 32 + l4 * 8]);
            int brow = wc * 64 + i * 16 + ln15;
            bf[i] = *(const bf16x8*)(&Bs[brow * 32 + l4 * 8]);
        }
#pragma unroll
        for (int i = 0; i < 4; ++i)
#pragma unroll
            for (int j = 0; j < 4; ++j)
                acc[i][j] = __builtin_amdgcn_mfma_f32_16x16x32_bf16(af[i], bf[j], acc[i][j], 0, 0, 0);
    }

    // ---- epilogue ----
#pragma unroll
    for (int j = 0; j < 4; ++j) {
        const int n = n0 + wc * 64 + j * 16 + ln15;
        float bval = 0.f;
        if constexpr (MODE == M_PROJQ || MODE == M_PROJK || MODE == M_PROJV || MODE == M_OUT)
            bval = bias[n];
#pragma unroll
        for (int i = 0; i < 4; ++i) {
#pragma unroll
            for (int r = 0; r < 4; ++r) {
                const int m = m0 + wr * 64 + i * 16 + l4 * 4 + r;
                float val = acc[i][j][r];
                if constexpr (MODE == M_PROJQ || MODE == M_PROJK) {
                    // m = t*NB + b -> Q[b][t][n]
                    unsigned short* o = (unsigned short*)Out;
                    o[(size_t)(m & 3) * (T1 * CC) + (size_t)(m >> 2) * CC + n] = f2bf(val + bval);
                } else if constexpr (MODE == M_PROJV) {
                    // m = s*NB + b -> Vt[b][n][s]
                    unsigned short* o = (unsigned short*)Out;
                    o[(size_t)(m & 3) * (CC * T2) + (size_t)n * T2 + (m >> 2)] = f2bf(val + bval);
                } else if constexpr (MODE == M_SCORES) {
                    unsigned short* o = (unsigned short*)Out + (size_t)z * T1 * T2;
                    o[(size_t)m * T2 + n] = f2bf(val * 0.03125f);
                } else if constexpr (MODE == M_PV) {
                    unsigned short* o = (unsigned short*)Out + (size_t)z * T1 * CC;
                    o[(size_t)m * CC + n] = f2bf(val);
                } else { // M_OUT: m = b*T1 + t -> out[t][b][n] fp32
                    float* o = (float*)Out;
                    o[(size_t)(m & (T1 - 1)) * (NB * CC) + (size_t)(m >> 11) * CC + n] = val + bval;
                }
            }
        }
    }
}

// ---------------- row softmax over T2, in-place on bf16 ----------------
__global__ __launch_bounds__(256) void softmax_k(unsigned short* __restrict__ SP) {
    const int tid = threadIdx.x, lane = tid & 63, w = tid >> 6;
    unsigned short* p = SP + (size_t)blockIdx.x * T2;
    u16x8 v = *(const u16x8*)(p + tid * 8);
    float f[8];
#pragma unroll
    for (int j = 0; j < 8; ++j) f[j] = bf2f(v[j]);
    float mx = f[0];
#pragma unroll
    for (int j = 1; j < 8; ++j) mx = fmaxf(mx, f[j]);
#pragma unroll
    for (int off = 32; off; off >>= 1) mx = fmaxf(mx, __shfl_xor(mx, off));
    __shared__ float red[8];
    if (lane == 0) red[w] = mx;
    __syncthreads();
    mx = fmaxf(fmaxf(red[0], red[1]), fmaxf(red[2], red[3]));
    float s = 0.f, e[8];
#pragma unroll
    for (int j = 0; j < 8; ++j) { e[j] = __expf(f[j] - mx); s += e[j]; }
#pragma unroll
    for (int off = 32; off; off >>= 1) s += __shfl_xor(s, off);
    if (lane == 0) red[4 + w] = s;
    __syncthreads();
    s = red[4] + red[5] + red[6] + red[7];
    float inv = 1.f / s;
    u16x8 o;
#pragma unroll
    for (int j = 0; j < 8; ++j) o[j] = f2bf(e[j] * inv);
    *(u16x8*)(p + tid * 8) = o;
}

// ---------------- launch ----------------
extern "C" void kernel_launch(void* const* d_in, const int* in_sizes, int n_in,
                              void* d_out, int out_size, void* d_ws, size_t ws_size,
                              hipStream_t stream) {
    const float* x1 = (const float*)d_in[0];
    const float* x2 = (const float*)d_in[1];
    // d_in[2] = x3 (unused by reference forward)
    const float* wq = (const float*)d_in[3];
    const float* bq = (const float*)d_in[4];
    const float* wk = (const float*)d_in[5];
    const float* bk = (const float*)d_in[6];
    const float* wv = (const float*)d_in[7];
    const float* bv = (const float*)d_in[8];
    const float* wu = (const float*)d_in[9];
    const float* bu = (const float*)d_in[10];

    char* ws = (char*)d_ws;
    // layout (bytes). Aliasing: SP reuses Xb1+Xb2 (dead after projections);
    // Ob reuses Qb (dead after scores).
    const size_t WB_OFF  = 0;          // 4 x 1M bf16 weights          (8 MB)
    const size_t XB1_OFF = 8388608;    // x1 bf16 [T1*B][C]            (16 MB)
    const size_t XB2_OFF = 25165824;   // x2 bf16 [T2*B][C]            (16 MB)
    const size_t SP_OFF  = 8388608;    // S/P [B][T1][T2] bf16 (alias) (32 MB)
    const size_t Q_OFF   = 41943040;   // Q  [B][T1][C] bf16           (16 MB)
    const size_t K_OFF   = 58720256;   // K  [B][T2][C] bf16           (16 MB)
    const size_t V_OFF   = 75497472;   // Vt [B][C][T2] bf16           (16 MB)
    const size_t O_OFF   = 41943040;   // O  [B][T1][C] bf16 (alias Q)
    const size_t WS_END  = 92274688;   // 88 MB
    if (ws_size < WS_END) return;

    unsigned short* wb  = (unsigned short*)(ws + WB_OFF);
    unsigned short* Xb1 = (unsigned short*)(ws + XB1_OFF);
    unsigned short* Xb2 = (unsigned short*)(ws + XB2_OFF);
    unsigned short* SP  = (unsigned short*)(ws + SP_OFF);
    unsigned short* Qb  = (unsigned short*)(ws + Q_OFF);
    unsigned short* Kb  = (unsigned short*)(ws + K_OFF);
    unsigned short* Vt  = (unsigned short*)(ws + V_OFF);
    unsigned short* Ob  = (unsigned short*)(ws + O_OFF);

    // one fused conversion pass: 20,971,520 elements / 8 per thread / 256 per block
    convall_k<<<dim3(10240), 256, 0, stream>>>(wq, wk, wv, wu, x1, x2, wb);

    // projections: M = 8192 (= t*NB+b rows), N = 1024, K = 1024 — all gll16 path
    gemm_bt<M_PROJQ, 1024><<<dim3(8, 64, 1), 256, 0, stream>>>(Xb1, wb,               bq, Qb);
    gemm_bt<M_PROJK, 1024><<<dim3(8, 64, 1), 256, 0, stream>>>(Xb2, wb + 1048576,     bk, Kb);
    gemm_bt<M_PROJV, 1024><<<dim3(8, 64, 1), 256, 0, stream>>>(Xb2, wb + 2 * 1048576, bv, Vt);

    // scores: per-b GEMM [T1 x T2], K = 1024, scaled 1/sqrt(C)=1/32, bf16 out
    gemm_bt<M_SCORES, 1024><<<dim3(16, 16, 4), 256, 0, stream>>>(Qb, Kb, nullptr, SP);

    // softmax over rows (8192 rows of 2048), in place
    softmax_k<<<dim3(8192), 256, 0, stream>>>(SP);

    // PV: per-b GEMM [T1 x C], K = T2 = 2048 (Vt rows are c, contiguous in s)
    gemm_bt<M_PV, 2048><<<dim3(8, 16, 4), 256, 0, stream>>>(SP, Vt, nullptr, Ob);

    // output projection: M = 8192 (= b*T1+t rows of O), N = 1024, K = 1024, fp32 out [T1,B,C]
    gemm_bt<M_OUT, 1024><<<dim3(8, 64, 1), 256, 0, stream>>>(Ob, wb + 3 * 1048576, bu, d_out);
}

// Round 11
// 374.331 us; speedup vs baseline: 1.0687x; 1.0687x over previous
//
#include <hip/hip_runtime.h>
#include <hip/hip_bf16.h>
#include <stdint.h>

#define T1 2048
#define T2 2048
#define NB 4
#define CC 1024

typedef __attribute__((ext_vector_type(4))) float   f32x4;
typedef __attribute__((ext_vector_type(8))) __bf16  bf16x8;
typedef __attribute__((ext_vector_type(8))) unsigned short u16x8;

__device__ __forceinline__ unsigned short f2bf(float f) {
    union { float f; uint32_t u; } x; x.f = f;
    uint32_t u = x.u;
    uint32_t r = (u + 0x7fffu + ((u >> 16) & 1u)) >> 16;
    return (unsigned short)r;
}

__device__ __forceinline__ float bf2f(unsigned short b) {
    return __uint_as_float(((uint32_t)b) << 16);
}

__device__ __forceinline__ void gll16(const void* g, void* l) {
    __builtin_amdgcn_global_load_lds((const __attribute__((address_space(1))) void*)g,
                                     (__attribute__((address_space(3))) void*)l, 16, 0, 0);
}

// ---------------- fused fp32 -> bf16 convert: wq,wk,wv,wu,x1,x2 -> contiguous bf16 ----------------
__global__ __launch_bounds__(256) void convall_k(const float* __restrict__ wq,
                                                 const float* __restrict__ wk,
                                                 const float* __restrict__ wv,
                                                 const float* __restrict__ wu,
                                                 const float* __restrict__ x1,
                                                 const float* __restrict__ x2,
                                                 unsigned short* __restrict__ dst) {
    size_t idx = ((size_t)blockIdx.x * 256 + threadIdx.x) * 8;
    const float* s;
    size_t off;
    if (idx < 4194304) {
        int wsel = (int)(idx >> 20);
        s = (wsel == 0) ? wq : (wsel == 1) ? wk : (wsel == 2) ? wv : wu;
        off = idx & 1048575;
    } else if (idx < 12582912) {
        s = x1; off = idx - 4194304;
    } else {
        s = x2; off = idx - 12582912;
    }
    f32x4 a = *(const f32x4*)(s + off);
    f32x4 b = *(const f32x4*)(s + off + 4);
    u16x8 o;
    o[0] = f2bf(a.x); o[1] = f2bf(a.y); o[2] = f2bf(a.z); o[3] = f2bf(a.w);
    o[4] = f2bf(b.x); o[5] = f2bf(b.y); o[6] = f2bf(b.z); o[7] = f2bf(b.w);
    *(u16x8*)(dst + idx) = o;
}

// ---------------- generic bf16 MFMA GEMM (A . B^T), m97-style 128^2 tile ----------------
// A: [M, KDIM] bf16 rows; B: [N, KDIM] bf16 rows. MODE controls epilogue mapping AND
// the XCD-aware 1D-grid block mapping: each XCD (assumed bid%8 round-robin) owns an
// L2-fitting sub-rectangle so shared panels stay resident in its private 4MB L2
// (R2 counters: FETCH 139MB vs 18MB ideal on proj GEMMs).
// M_KV = merged K+V projection (N=2048, wk||wv adjacent): grid 1024 = 4 blocks/CU,
// an intentional occupancy A/B against M_PROJQ's 512 = 2 blocks/CU.
enum { M_PROJQ = 0, M_KV, M_SCORES, M_PV, M_OUT };

template <int MODE, int KDIM>
__global__ __launch_bounds__(256) void gemm_bt(const unsigned short* __restrict__ Aptr,
                                               const unsigned short* __restrict__ Bptr,
                                               const float* __restrict__ bias,
                                               const float* __restrict__ bias2,
                                               void* __restrict__ Out,
                                               void* __restrict__ Out2) {
    __shared__ unsigned short As[128 * 32];
    __shared__ unsigned short Bs[128 * 32];

    const int tid  = threadIdx.x;
    const int lane = tid & 63;
    const int w    = tid >> 6;
    const int wr   = w >> 1, wc = w & 1;

    // ---- XCD-aware block mapping (bijective) ----
    const int bid = blockIdx.x;
    const int xcd = bid & 7;
    const int i   = bid >> 3;
    int m0, n0, z = 0;
    if constexpr (MODE == M_SCORES) {
        // grid 1024: xcd = (z, mhalf); 8 m-blocks (fast) x 16 n-blocks. Res: 2MB Q-half + 256KB K-stripe.
        z = xcd >> 1;
        const int mhalf = xcd & 1;
        const int nblk = i >> 3, mloc = i & 7;
        m0 = (mhalf * 8 + mloc) * 128;
        n0 = nblk * 128;
    } else if constexpr (MODE == M_PV) {
        // grid 512: xcd = (z, nhalf); 4 n-blocks (fast) x 16 m-blocks. Res: 2MB Vt-half + 512KB P-stripe.
        z = xcd >> 1;
        const int nhalf = xcd & 1;
        const int nloc = i & 3, mblk = i >> 2;
        m0 = mblk * 128;
        n0 = (nhalf * 4 + nloc) * 128;
    } else if constexpr (MODE == M_KV) {
        // grid 1024: xcd owns m-rows [1024*xcd,+1024) x all 2048 n. mloc fast.
        // Res: 2MB A-slice + 256KB W-stripe (B=4MB cycled once per XCD).
        const int mloc = i & 7, nblk = i >> 3;   // nblk 0..15
        m0 = (xcd * 8 + mloc) * 128;
        n0 = nblk * 128;
    } else {
        // M_PROJQ / M_OUT, grid 512: xcd owns m-rows [1024*xcd,+1024) x all 1024 n.
        const int mloc = i & 7, nblk = i >> 3;   // nblk 0..7
        m0 = (xcd * 8 + mloc) * 128;
        n0 = nblk * 128;
    }

    size_t aoff = 0, boff = 0;
    if constexpr (MODE == M_SCORES) { aoff = (size_t)z * T1 * CC; boff = (size_t)z * T2 * CC; }
    if constexpr (MODE == M_PV)     { aoff = (size_t)z * T1 * T2; boff = (size_t)z * CC * T2; }

    const unsigned short* Ab = Aptr + aoff;
    const unsigned short* Bb = Bptr + boff;

    f32x4 acc[4][4] = {};

    const int ln15 = lane & 15;
    const int l4   = lane >> 4;
    const int srow = tid >> 2, sseg = tid & 3;

    for (int kt = 0; kt < KDIM; kt += 32) {
        __syncthreads();
#pragma unroll
        for (int p = 0; p < 2; ++p) {
            int c = p * 256 + tid;
            int row = p * 64 + srow;
            gll16(Ab + (size_t)(m0 + row) * KDIM + kt + sseg * 8, &As[c * 8]);
        }
#pragma unroll
        for (int p = 0; p < 2; ++p) {
            int c = p * 256 + tid;
            int row = p * 64 + srow;
            gll16(Bb + (size_t)(n0 + row) * KDIM + kt + sseg * 8, &Bs[c * 8]);
        }
        __syncthreads();
        bf16x8 af[4], bf[4];
#pragma unroll
        for (int i2 = 0; i2 < 4; ++i2) {
            int arow = wr * 64 + i2 * 16 + ln15;
            af[i2] = *(const bf16x8*)(&As[arow * 32 + l4 * 8]);
            int brow = wc * 64 + i2 * 16 + ln15;
            bf[i2] = *(const bf16x8*)(&Bs[brow * 32 + l4 * 8]);
        }
#pragma unroll
        for (int i2 = 0; i2 < 4; ++i2)
#pragma unroll
            for (int j = 0; j < 4; ++j)
                acc[i2][j] = __builtin_amdgcn_mfma_f32_16x16x32_bf16(af[i2], bf[j], acc[i2][j], 0, 0, 0);
    }

    // ---- epilogue ----
#pragma unroll
    for (int j = 0; j < 4; ++j) {
        const int n = n0 + wc * 64 + j * 16 + ln15;
        float bval = 0.f;
        if constexpr (MODE == M_PROJQ || MODE == M_OUT)
            bval = bias[n];
        if constexpr (MODE == M_KV)
            bval = (n < CC) ? bias[n] : bias2[n - CC];
#pragma unroll
        for (int i2 = 0; i2 < 4; ++i2) {
#pragma unroll
            for (int r = 0; r < 4; ++r) {
                const int m = m0 + wr * 64 + i2 * 16 + l4 * 4 + r;
                float val = acc[i2][j][r];
                if constexpr (MODE == M_PROJQ) {
                    // m = t*NB + b -> Q[b][t][n]
                    unsigned short* o = (unsigned short*)Out;
                    o[(size_t)(m & 3) * (T1 * CC) + (size_t)(m >> 2) * CC + n] = f2bf(val + bval);
                } else if constexpr (MODE == M_KV) {
                    // m = s*NB + b; n<CC -> K[b][s][n], n>=CC -> Vt[b][n-CC][s]
                    if (n < CC) {
                        unsigned short* o = (unsigned short*)Out;
                        o[(size_t)(m & 3) * (T2 * CC) + (size_t)(m >> 2) * CC + n] = f2bf(val + bval);
                    } else {
                        unsigned short* o = (unsigned short*)Out2;
                        o[(size_t)(m & 3) * (CC * T2) + (size_t)(n - CC) * T2 + (m >> 2)] = f2bf(val + bval);
                    }
                } else if constexpr (MODE == M_SCORES) {
                    unsigned short* o = (unsigned short*)Out + (size_t)z * T1 * T2;
                    o[(size_t)m * T2 + n] = f2bf(val * 0.03125f);
                } else if constexpr (MODE == M_PV) {
                    unsigned short* o = (unsigned short*)Out + (size_t)z * T1 * CC;
                    o[(size_t)m * CC + n] = f2bf(val);
                } else { // M_OUT: m = b*T1 + t -> out[t][b][n] fp32
                    float* o = (float*)Out;
                    o[(size_t)(m & (T1 - 1)) * (NB * CC) + (size_t)(m >> 11) * CC + n] = val + bval;
                }
            }
        }
    }
}

// ---------------- row softmax over T2, in-place on bf16 ----------------
__global__ __launch_bounds__(256) void softmax_k(unsigned short* __restrict__ SP) {
    const int tid = threadIdx.x, lane = tid & 63, w = tid >> 6;
    unsigned short* p = SP + (size_t)blockIdx.x * T2;
    u16x8 v = *(const u16x8*)(p + tid * 8);
    float f[8];
#pragma unroll
    for (int j = 0; j < 8; ++j) f[j] = bf2f(v[j]);
    float mx = f[0];
#pragma unroll
    for (int j = 1; j < 8; ++j) mx = fmaxf(mx, f[j]);
#pragma unroll
    for (int off = 32; off; off >>= 1) mx = fmaxf(mx, __shfl_xor(mx, off));
    __shared__ float red[8];
    if (lane == 0) red[w] = mx;
    __syncthreads();
    mx = fmaxf(fmaxf(red[0], red[1]), fmaxf(red[2], red[3]));
    float s = 0.f, e[8];
#pragma unroll
    for (int j = 0; j < 8; ++j) { e[j] = __expf(f[j] - mx); s += e[j]; }
#pragma unroll
    for (int off = 32; off; off >>= 1) s += __shfl_xor(s, off);
    if (lane == 0) red[4 + w] = s;
    __syncthreads();
    s = red[4] + red[5] + red[6] + red[7];
    float inv = 1.f / s;
    u16x8 o;
#pragma unroll
    for (int j = 0; j < 8; ++j) o[j] = f2bf(e[j] * inv);
    *(u16x8*)(p + tid * 8) = o;
}

// ---------------- launch ----------------
extern "C" void kernel_launch(void* const* d_in, const int* in_sizes, int n_in,
                              void* d_out, int out_size, void* d_ws, size_t ws_size,
                              hipStream_t stream) {
    const float* x1 = (const float*)d_in[0];
    const float* x2 = (const float*)d_in[1];
    // d_in[2] = x3 (unused by reference forward)
    const float* wq = (const float*)d_in[3];
    const float* bq = (const float*)d_in[4];
    const float* wk = (const float*)d_in[5];
    const float* bk = (const float*)d_in[6];
    const float* wv = (const float*)d_in[7];
    const float* bv = (const float*)d_in[8];
    const float* wu = (const float*)d_in[9];
    const float* bu = (const float*)d_in[10];

    char* ws = (char*)d_ws;
    const size_t WB_OFF  = 0;          // 4 x 1M bf16 weights          (8 MB)
    const size_t XB1_OFF = 8388608;    // x1 bf16 [T1*B][C]            (16 MB)
    const size_t XB2_OFF = 25165824;   // x2 bf16 [T2*B][C]            (16 MB)
    const size_t SP_OFF  = 8388608;    // S/P bf16 (alias Xb1+Xb2)     (32 MB)
    const size_t Q_OFF   = 41943040;   // Q  [B][T1][C] bf16           (16 MB)
    const size_t K_OFF   = 58720256;   // K  [B][T2][C] bf16           (16 MB)
    const size_t V_OFF   = 75497472;   // Vt [B][C][T2] bf16           (16 MB)
    const size_t O_OFF   = 41943040;   // O  bf16 (alias Q)
    const size_t WS_END  = 92274688;   // 88 MB
    if (ws_size < WS_END) return;

    unsigned short* wb  = (unsigned short*)(ws + WB_OFF);
    unsigned short* Xb1 = (unsigned short*)(ws + XB1_OFF);
    unsigned short* Xb2 = (unsigned short*)(ws + XB2_OFF);
    unsigned short* SP  = (unsigned short*)(ws + SP_OFF);
    unsigned short* Qb  = (unsigned short*)(ws + Q_OFF);
    unsigned short* Kb  = (unsigned short*)(ws + K_OFF);
    unsigned short* Vt  = (unsigned short*)(ws + V_OFF);
    unsigned short* Ob  = (unsigned short*)(ws + O_OFF);

    convall_k<<<dim3(10240), 256, 0, stream>>>(wq, wk, wv, wu, x1, x2, wb);

    // Q projection: M=8192, N=1024 — 512 blocks (2/CU)  [occupancy A/B arm 1]
    gemm_bt<M_PROJQ, 1024><<<dim3(512), 256, 0, stream>>>(Xb1, wb, bq, nullptr, Qb, nullptr);

    // merged K+V projection: M=8192, N=2048 (wk||wv) — 1024 blocks (4/CU)  [arm 2]
    gemm_bt<M_KV, 1024><<<dim3(1024), 256, 0, stream>>>(Xb2, wb + 1048576, bk, bv, Kb, Vt);

    // scores: per-b [T1 x T2], K=1024, scaled 1/32
    gemm_bt<M_SCORES, 1024><<<dim3(1024), 256, 0, stream>>>(Qb, Kb, nullptr, nullptr, SP, nullptr);

    // softmax over rows (8192 rows of 2048), in place
    softmax_k<<<dim3(8192), 256, 0, stream>>>(SP);

    // PV: per-b [T1 x C], K=2048
    gemm_bt<M_PV, 2048><<<dim3(512), 256, 0, stream>>>(SP, Vt, nullptr, nullptr, Ob, nullptr);

    // output projection: M=8192, N=1024, K=1024, fp32 out [T1,B,C]
    gemm_bt<M_OUT, 1024><<<dim3(512), 256, 0, stream>>>(Ob, wb + 3 * 1048576, bu, nullptr, d_out, nullptr);
}